// Round 8
// baseline (382.968 us; speedup 1.0000x reference)
//
#include <hip/hip_runtime.h>

#define S_LEN 4096
#define DMODEL 768
#define NHEAD 12
#define HD 64

typedef __bf16 bf16x8 __attribute__((ext_vector_type(8)));
typedef __bf16 bf16x4 __attribute__((ext_vector_type(4)));
typedef float f32x4 __attribute__((ext_vector_type(4)));
typedef float f32x16 __attribute__((ext_vector_type(16)));
typedef unsigned short u16x8 __attribute__((ext_vector_type(8)));
typedef unsigned short u16x4 __attribute__((ext_vector_type(4)));
typedef _Float16 f16x4 __attribute__((ext_vector_type(4)));

#if __has_builtin(__builtin_amdgcn_exp2f)
#define EXP2F(x) __builtin_amdgcn_exp2f(x)
#else
#define EXP2F(x) exp2f(x)
#endif

#define MFMA32(a, b, c) __builtin_amdgcn_mfma_f32_32x32x16_bf16(a, b, c, 0, 0, 0)

__device__ __forceinline__ unsigned short f2bf(float f) {
  unsigned int u = __float_as_uint(f);
  u += 0x7fffu + ((u >> 16) & 1u);   // round-to-nearest-even
  return (unsigned short)(u >> 16);
}

__device__ __forceinline__ void gload_lds16(const void* g, void* l) {
  __builtin_amdgcn_global_load_lds(
      (__attribute__((address_space(1))) void*)g,
      (__attribute__((address_space(3))) void*)l, 16, 0, 0);
}

// ---------------- fp32 -> bf16 conversion ----------------
struct CvtArgs {
  const float* src[7];
  unsigned short* dst[7];
  int n[7];
};

__global__ __launch_bounds__(256) void cvt_kernel(CvtArgs a) {
  const int seg = blockIdx.y;
  const int n = a.n[seg];
  const int i = (blockIdx.x * 256 + threadIdx.x) * 8;
  if (i >= n) return;
  const float* s = a.src[seg] + i;
  u16x8 o;
#pragma unroll
  for (int j = 0; j < 8; ++j) o[j] = f2bf(s[j]);
  *reinterpret_cast<u16x8*>(a.dst[seg] + i) = o;
}

// ---------------- fused Q/K/V projection: z = 0(Q) 1(K) 2(V) ------------
// z<2 -> [h][s][64] (Q scaled); z==2 -> transposed [h][hd][s] with kv
// bits 2<->3 swapped (PV B-fragment register order).
struct QkvArgs {
  const unsigned short* A[3];
  const unsigned short* W[3];
  const float* bias[3];
  unsigned short* dst[3];
  float scale[3];
};

__global__ __launch_bounds__(256) void qkv_gemm(QkvArgs a) {
  __shared__ unsigned char lds[32768];  // A tile 16KB | W tile 16KB
  const int z = blockIdx.z;
  const unsigned short* __restrict__ A = a.A[z];
  const unsigned short* __restrict__ B = a.W[z];
  const float* __restrict__ bias = a.bias[z];
  unsigned short* __restrict__ dst = a.dst[z];
  const float scale = a.scale[z];

  const int tid = threadIdx.x;
  const int lane = tid & 63;
  const int w = tid >> 6;
  const int wr = w >> 1, wc = w & 1;
  const int c = lane & 15, g = lane >> 4;
  const int m0 = blockIdx.x * 128;
  const int n0 = blockIdx.y * 128;

  f32x4 acc[4][4] = {};

  for (int kt = 0; kt < DMODEL / 64; ++kt) {
#pragma unroll
    for (int p = 0; p < 4; ++p) {
      const int te = p * 256 + tid;
      const int row = te >> 3;
      const int sb = ((te & 7) * 16) ^ ((row & 7) << 4);
      gload_lds16(A + (size_t)(m0 + row) * DMODEL + kt * 64 + (sb >> 1), &lds[te * 16]);
      gload_lds16(B + (size_t)(n0 + row) * DMODEL + kt * 64 + (sb >> 1), &lds[16384 + te * 16]);
    }
    __syncthreads();

    bf16x8 af[4][2], bfr[4][2];
#pragma unroll
    for (int mb = 0; mb < 4; ++mb)
#pragma unroll
      for (int ks = 0; ks < 2; ++ks) {
        const int row = wr * 64 + mb * 16 + c;
        const int byte = (ks * 64 + g * 16) ^ ((row & 7) << 4);
        af[mb][ks] = *reinterpret_cast<const bf16x8*>(&lds[row * 128 + byte]);
      }
#pragma unroll
    for (int nb = 0; nb < 4; ++nb)
#pragma unroll
      for (int ks = 0; ks < 2; ++ks) {
        const int row = wc * 64 + nb * 16 + c;
        const int byte = (ks * 64 + g * 16) ^ ((row & 7) << 4);
        bfr[nb][ks] = *reinterpret_cast<const bf16x8*>(&lds[16384 + row * 128 + byte]);
      }
    __builtin_amdgcn_s_setprio(1);
#pragma unroll
    for (int ks = 0; ks < 2; ++ks)
#pragma unroll
      for (int mb = 0; mb < 4; ++mb)
#pragma unroll
        for (int nb = 0; nb < 4; ++nb)
          acc[mb][nb] = __builtin_amdgcn_mfma_f32_16x16x32_bf16(
              af[mb][ks], bfr[nb][ks], acc[mb][nb], 0, 0, 0);
    __builtin_amdgcn_s_setprio(0);
    __syncthreads();
  }

#pragma unroll
  for (int mb = 0; mb < 4; ++mb) {
#pragma unroll
    for (int nb = 0; nb < 4; ++nb) {
      const int n = n0 + wc * 64 + nb * 16 + c;
      const float bv = bias[n];
#pragma unroll
      for (int r = 0; r < 4; ++r) {
        const int m = m0 + wr * 64 + mb * 16 + g * 4 + r;
        const float v = (acc[mb][nb][r] + bv) * scale;
        const int hh = n >> 6, hd = n & 63;
        if (z != 2) {
          dst[((size_t)hh * S_LEN + m) * HD + hd] = f2bf(v);
        } else {
          const int mp = (m & ~12) | ((m & 4) << 1) | ((m & 8) >> 1);
          dst[((size_t)hh * HD + hd) * S_LEN + mp] = f2bf(v);
        }
      }
    }
  }
}

// ---------------- output projection: fp32 out ----------------
__global__ __launch_bounds__(256) void gemm_out(
    const unsigned short* __restrict__ A, const unsigned short* __restrict__ B,
    const float* __restrict__ bias, float* __restrict__ dst) {
  __shared__ unsigned char lds[32768];
  const int tid = threadIdx.x;
  const int lane = tid & 63;
  const int w = tid >> 6;
  const int wr = w >> 1, wc = w & 1;
  const int c = lane & 15, g = lane >> 4;
  const int m0 = blockIdx.x * 128;
  const int n0 = blockIdx.y * 128;

  f32x4 acc[4][4] = {};

  for (int kt = 0; kt < DMODEL / 64; ++kt) {
#pragma unroll
    for (int p = 0; p < 4; ++p) {
      const int te = p * 256 + tid;
      const int row = te >> 3;
      const int sb = ((te & 7) * 16) ^ ((row & 7) << 4);
      gload_lds16(A + (size_t)(m0 + row) * DMODEL + kt * 64 + (sb >> 1), &lds[te * 16]);
      gload_lds16(B + (size_t)(n0 + row) * DMODEL + kt * 64 + (sb >> 1), &lds[16384 + te * 16]);
    }
    __syncthreads();

    bf16x8 af[4][2], bfr[4][2];
#pragma unroll
    for (int mb = 0; mb < 4; ++mb)
#pragma unroll
      for (int ks = 0; ks < 2; ++ks) {
        const int row = wr * 64 + mb * 16 + c;
        const int byte = (ks * 64 + g * 16) ^ ((row & 7) << 4);
        af[mb][ks] = *reinterpret_cast<const bf16x8*>(&lds[row * 128 + byte]);
      }
#pragma unroll
    for (int nb = 0; nb < 4; ++nb)
#pragma unroll
      for (int ks = 0; ks < 2; ++ks) {
        const int row = wc * 64 + nb * 16 + c;
        const int byte = (ks * 64 + g * 16) ^ ((row & 7) << 4);
        bfr[nb][ks] = *reinterpret_cast<const bf16x8*>(&lds[16384 + row * 128 + byte]);
      }
    __builtin_amdgcn_s_setprio(1);
#pragma unroll
    for (int ks = 0; ks < 2; ++ks)
#pragma unroll
      for (int mb = 0; mb < 4; ++mb)
#pragma unroll
        for (int nb = 0; nb < 4; ++nb)
          acc[mb][nb] = __builtin_amdgcn_mfma_f32_16x16x32_bf16(
              af[mb][ks], bfr[nb][ks], acc[mb][nb], 0, 0, 0);
    __builtin_amdgcn_s_setprio(0);
    __syncthreads();
  }

#pragma unroll
  for (int mb = 0; mb < 4; ++mb)
#pragma unroll
    for (int nb = 0; nb < 4; ++nb) {
      const int n = n0 + wc * 64 + nb * 16 + c;
      const float bv = bias[n];
#pragma unroll
      for (int r = 0; r < 4; ++r) {
        const int m = m0 + wr * 64 + mb * 16 + g * 4 + r;
        dst[(size_t)m * DMODEL + n] = acc[mb][nb][r] + bv;
      }
    }
}

// ---------------- flash attention, 8-wave blocks, kv-split-4 ------------
// grid = (S/256, H, 4); block = 512 (8 waves x 32 q). KV tile 64.
// K/V staging amortized over 256 q-rows (2 loads/thread/tile).
// Transposed-chunk LDS (conflict-free b128). Triple buffer, one barrier
// per kt, prefetch depth 2, counted vmcnt(2) (r6-verified schedule).
__global__ __launch_bounds__(512, 6) void attn_kernel(
    const unsigned short* __restrict__ qh,   // [H][S][64], pre-scaled
    const unsigned short* __restrict__ kh,   // [H][S][64]
    const unsigned short* __restrict__ vtp,  // [H][64][S], kv bits2<->3 swapped
    _Float16* __restrict__ pacc,             // [4][H][S][64] (values /64)
    float* __restrict__ prs) {               // [4][H][S]     (values /64)
  __shared__ unsigned char lds[49152];  // 3 x (K 8KB | Vt 8KB)
  const int tid = threadIdx.x;
  const int lane = tid & 63;
  const int w = tid >> 6;          // 0..7
  const int c5 = lane & 31;
  const int h2 = lane >> 5;
  const int hh = blockIdx.y;
  const int split = blockIdx.z;
  const int qw = blockIdx.x * 256 + w * 32;
  const int kv0 = split * (S_LEN / 4);
  const int nkt = (S_LEN / 4) / 64;   // 16

  // Q B-fragments: col = q = c5, k = ks*16 + h2*8 + i
  bf16x8 qa[4];
#pragma unroll
  for (int ks = 0; ks < 4; ++ks)
    qa[ks] = *reinterpret_cast<const bf16x8*>(
        qh + ((size_t)hh * S_LEN + qw + c5) * HD + ks * 16 + h2 * 8);

  // transposed-chunk staging: LDS[tid*16] <- K[row = tid&63][kchunk = tid>>6]
  // 512 threads cover the full 64x64 tile (8 kchunks) in ONE load each.
  const unsigned short* ksrc =
      kh + ((size_t)hh * S_LEN + kv0 + (tid & 63)) * HD + (tid >> 6) * 8;
  const unsigned short* vsrc =
      vtp + ((size_t)hh * HD + (tid & 63)) * S_LEN + kv0 + (tid >> 6) * 8;
  const int dL = tid * 16;

  auto stage = [&](int bo) {
    gload_lds16(ksrc, &lds[bo + dL]);
    gload_lds16(vsrc, &lds[bo + 8192 + dL]);
    ksrc += 64 * HD;
    vsrc += 64;
  };

  // prologue: stage tiles 0,1 into bufs 0,1 (4 loads in flight)
  stage(0);
  stage(16384);

  f32x16 accO[2] = {};
  float rs0 = 0.f, rs1 = 0.f, rs2 = 0.f, rs3 = 0.f;

  auto compute = [&](const unsigned char* Kb, const unsigned char* Vb) {
    // S^T[kv][q] = mfma(K as A, Q as B)
    f32x16 s0 = {}, s1 = {};
    __builtin_amdgcn_s_setprio(1);
#pragma unroll
    for (int ks = 0; ks < 4; ++ks) {
      const unsigned char* kbase = Kb + (ks * 2 + h2) * 1024 + c5 * 16;
      const bf16x8 k0 = *reinterpret_cast<const bf16x8*>(kbase);
      const bf16x8 k1 = *reinterpret_cast<const bf16x8*>(kbase + 512);
      s0 = MFMA32(k0, qa[ks], s0);
      s1 = MFMA32(k1, qa[ks], s1);
    }
    __builtin_amdgcn_s_setprio(0);

    // fused softmax + PV per 8-kv quadrant
#pragma unroll
    for (int t = 0; t < 2; ++t)
#pragma unroll
      for (int ss = 0; ss < 2; ++ss) {
        const unsigned char* vbase = Vb + (t * 4 + ss * 2 + h2) * 1024 + c5 * 16;
        const bf16x8 va0 = *reinterpret_cast<const bf16x8*>(vbase);
        const bf16x8 va1 = *reinterpret_cast<const bf16x8*>(vbase + 512);
        bf16x8 pb;
        float racc = 0.f;
#pragma unroll
        for (int r = 0; r < 8; ++r) {
          const float e = EXP2F(t ? s1[ss * 8 + r] : s0[ss * 8 + r]);
          racc += e;
          pb[r] = (__bf16)e;
        }
        if (t == 0) { if (ss == 0) rs0 += racc; else rs1 += racc; }
        else        { if (ss == 0) rs2 += racc; else rs3 += racc; }
        __builtin_amdgcn_s_setprio(1);
        accO[0] = MFMA32(va0, pb, accO[0]);
        accO[1] = MFMA32(va1, pb, accO[1]);
        __builtin_amdgcn_s_setprio(0);
      }
  };

  int boC = 0;          // buffer being computed (tile t)
  int boS = 32768;      // buffer to stage into (tile t+2)
  for (int t = 0; t < nkt; ++t) {
    if (t + 2 < nkt) {
      asm volatile("s_waitcnt vmcnt(2)" ::: "memory");
      __builtin_amdgcn_sched_barrier(0);
      __builtin_amdgcn_s_barrier();
      __builtin_amdgcn_sched_barrier(0);
      stage(boS);
    } else if (t + 1 < nkt) {
      asm volatile("s_waitcnt vmcnt(2)" ::: "memory");
      __builtin_amdgcn_sched_barrier(0);
      __builtin_amdgcn_s_barrier();
      __builtin_amdgcn_sched_barrier(0);
    } else {
      asm volatile("s_waitcnt vmcnt(0)" ::: "memory");
      __builtin_amdgcn_sched_barrier(0);
      __builtin_amdgcn_s_barrier();
      __builtin_amdgcn_sched_barrier(0);
    }
    compute(&lds[boC], &lds[boC + 8192]);
    boC += 16384; if (boC == 49152) boC = 0;
    boS += 16384; if (boS == 49152) boS = 0;
  }

  // partial sums out (scaled by 1/64 for f16 range)
  float rsA = (rs0 + rs1) + (rs2 + rs3);
  rsA += __shfl_xor(rsA, 32);
  const size_t hqbase = ((size_t)split * NHEAD + hh) * S_LEN + qw + c5;
  if (h2 == 0) prs[hqbase] = rsA * 0.015625f;
#pragma unroll
  for (int dt = 0; dt < 2; ++dt)
#pragma unroll
    for (int rr = 0; rr < 4; ++rr) {
      f16x4 o;
#pragma unroll
      for (int j = 0; j < 4; ++j)
        o[j] = (_Float16)(accO[dt][rr * 4 + j] * 0.015625f);
      *reinterpret_cast<f16x4*>(
          pacc + hqbase * 64 + dt * 32 + rr * 8 + h2 * 4) = o;
    }
}

// ---------------- combine 4 kv-split partials -> attb bf16 ---------------
__global__ __launch_bounds__(256) void combine_kernel(
    const _Float16* __restrict__ pacc, const float* __restrict__ prs,
    unsigned short* __restrict__ attb) {
  const int idx = blockIdx.x * 256 + threadIdx.x;  // 786432 total
  const int hq = idx >> 4;            // h*4096 + q
  const int d4 = (idx & 15) * 4;
  const int h = hq >> 12;
  const int q = hq & 4095;
  const int HS = NHEAD * S_LEN;
  const size_t o0 = (size_t)hq * 64 + d4;
  float acc4[4] = {0.f, 0.f, 0.f, 0.f};
  float rs = 0.f;
#pragma unroll
  for (int k = 0; k < 4; ++k) {
    const f16x4 av = *reinterpret_cast<const f16x4*>(pacc + o0 + (size_t)k * HS * 64);
#pragma unroll
    for (int j = 0; j < 4; ++j) acc4[j] += (float)av[j];
    rs += prs[hq + k * HS];
  }
  const float inv = 1.f / rs;
  u16x4 ov;
#pragma unroll
  for (int j = 0; j < 4; ++j) ov[j] = f2bf(acc4[j] * inv);
  *reinterpret_cast<u16x4*>(attb + (size_t)q * DMODEL + h * HD + d4) = ov;
}

// ---------------- launch ----------------
extern "C" void kernel_launch(void* const* d_in, const int* in_sizes, int n_in,
                              void* d_out, int out_size, void* d_ws, size_t ws_size,
                              hipStream_t stream) {
  (void)in_sizes; (void)n_in; (void)out_size;
  const float* q  = (const float*)d_in[0];
  const float* k  = (const float*)d_in[1];
  const float* v  = (const float*)d_in[2];
  const float* Wq = (const float*)d_in[3];
  const float* bq = (const float*)d_in[4];
  const float* Wk = (const float*)d_in[5];
  const float* bk = (const float*)d_in[6];
  const float* Wv = (const float*)d_in[7];
  const float* bv = (const float*)d_in[8];
  const float* Wo = (const float*)d_in[9];
  const float* bo = (const float*)d_in[10];
  float* out = (float*)d_out;

  const size_t SD = (size_t)S_LEN * DMODEL;    // 3145728
  const size_t DD = (size_t)DMODEL * DMODEL;   // 589824
  if (ws_size < (7 * SD + 4 * DD) * 2) return;

  // ws layout (u16 units). Liveness ledger:
  //  pacc [0..4SD)  f16 [4][H][S][64] -- written by attn, read by combine.
  //    Aliases (all dead before attn runs): qbf [0..SD), kbf [SD..2SD),
  //    vbf [2SD..3SD) (dead after qkv); wqb/wkb/wvb [3SD..3SD+3DD)
  //    (dead after qkv; 3SD+3DD < 4SD).
  //  qhb [4SD..5SD)  -- read by attn, dead after; attb aliases it
  //    (written by combine, read by gemm_out).
  //  khb [5SD..6SD), vtb [6SD..7SD) -- dead after attn.
  //  prs [7SD..7SD+393216)  f32 [4][H][S].
  //  wob [7SD+393216..+DD)  -- live until gemm_out. Fits: 393216+DD < 4DD.
  unsigned short* ws   = (unsigned short*)d_ws;
  unsigned short* qbf  = ws;
  unsigned short* kbf  = ws + SD;
  unsigned short* vbf  = ws + 2 * SD;
  unsigned short* wqb  = ws + 3 * SD;
  unsigned short* wkb  = ws + 3 * SD + DD;
  unsigned short* wvb  = ws + 3 * SD + 2 * DD;
  unsigned short* qhb  = ws + 4 * SD;   // [H][S][64]
  unsigned short* khb  = ws + 5 * SD;   // [H][S][64]
  unsigned short* vtb  = ws + 6 * SD;   // [H][64][S] (kv-permuted)
  float*          prs  = (float*)(ws + 7 * SD);          // [4][H][S]
  unsigned short* wob  = ws + 7 * SD + 393216;
  _Float16*       pacc = (_Float16*)ws;                  // [4][H][S][64]
  unsigned short* attb = ws + 4 * SD;                    // alias qhb

  CvtArgs ca;
  ca.src[0] = q;  ca.dst[0] = qbf; ca.n[0] = (int)SD;
  ca.src[1] = k;  ca.dst[1] = kbf; ca.n[1] = (int)SD;
  ca.src[2] = v;  ca.dst[2] = vbf; ca.n[2] = (int)SD;
  ca.src[3] = Wq; ca.dst[3] = wqb; ca.n[3] = (int)DD;
  ca.src[4] = Wk; ca.dst[4] = wkb; ca.n[4] = (int)DD;
  ca.src[5] = Wv; ca.dst[5] = wvb; ca.n[5] = (int)DD;
  ca.src[6] = Wo; ca.dst[6] = wob; ca.n[6] = (int)DD;
  cvt_kernel<<<dim3(1536, 7), 256, 0, stream>>>(ca);

  QkvArgs qa;
  qa.A[0] = qbf; qa.W[0] = wqb; qa.bias[0] = bq; qa.dst[0] = qhb;
  qa.scale[0] = 0.18033688011112042f;  // (1/8) * log2(e)
  qa.A[1] = kbf; qa.W[1] = wkb; qa.bias[1] = bk; qa.dst[1] = khb;
  qa.scale[1] = 1.0f;
  qa.A[2] = vbf; qa.W[2] = wvb; qa.bias[2] = bv; qa.dst[2] = vtb;
  qa.scale[2] = 1.0f;
  qkv_gemm<<<dim3(32, 6, 3), 256, 0, stream>>>(qa);

  attn_kernel<<<dim3(S_LEN / 256, NHEAD, 4), 512, 0, stream>>>(
      qhb, khb, vtb, pacc, prs);

  combine_kernel<<<dim3((NHEAD * S_LEN * 16) / 256), 256, 0, stream>>>(
      pacc, prs, attb);

  gemm_out<<<dim3(32, 6), 256, 0, stream>>>(attb, wob, bo, out);
}

// Round 9
// 121.558 us; speedup vs baseline: 3.1505x; 3.1505x over previous
//
#include <hip/hip_runtime.h>

#define S_LEN 4096
#define DMODEL 768
#define NHEAD 12
#define HD 64

typedef __bf16 bf16x8 __attribute__((ext_vector_type(8)));
typedef __bf16 bf16x4 __attribute__((ext_vector_type(4)));
typedef float f32x4 __attribute__((ext_vector_type(4)));
typedef float f32x16 __attribute__((ext_vector_type(16)));
typedef unsigned short u16x8 __attribute__((ext_vector_type(8)));
typedef unsigned short u16x4 __attribute__((ext_vector_type(4)));
typedef _Float16 f16x4 __attribute__((ext_vector_type(4)));

#if __has_builtin(__builtin_amdgcn_exp2f)
#define EXP2F(x) __builtin_amdgcn_exp2f(x)
#else
#define EXP2F(x) exp2f(x)
#endif

#define MFMA32(a, b, c) __builtin_amdgcn_mfma_f32_32x32x16_bf16(a, b, c, 0, 0, 0)

__device__ __forceinline__ unsigned short f2bf(float f) {
  unsigned int u = __float_as_uint(f);
  u += 0x7fffu + ((u >> 16) & 1u);   // round-to-nearest-even
  return (unsigned short)(u >> 16);
}

__device__ __forceinline__ void gload_lds16(const void* g, void* l) {
  __builtin_amdgcn_global_load_lds(
      (__attribute__((address_space(1))) void*)g,
      (__attribute__((address_space(3))) void*)l, 16, 0, 0);
}

// ---------------- fp32 -> bf16 conversion ----------------
struct CvtArgs {
  const float* src[7];
  unsigned short* dst[7];
  int n[7];
};

__global__ __launch_bounds__(256) void cvt_kernel(CvtArgs a) {
  const int seg = blockIdx.y;
  const int n = a.n[seg];
  const int i = (blockIdx.x * 256 + threadIdx.x) * 8;
  if (i >= n) return;
  const float* s = a.src[seg] + i;
  u16x8 o;
#pragma unroll
  for (int j = 0; j < 8; ++j) o[j] = f2bf(s[j]);
  *reinterpret_cast<u16x8*>(a.dst[seg] + i) = o;
}

// ---------------- fused Q/K/V projection: z = 0(Q) 1(K) 2(V) ------------
// z<2 -> [h][s][64] (Q scaled); z==2 -> transposed [h][hd][s] with kv
// bits 2<->3 swapped (PV B-fragment register order).
struct QkvArgs {
  const unsigned short* A[3];
  const unsigned short* W[3];
  const float* bias[3];
  unsigned short* dst[3];
  float scale[3];
};

__global__ __launch_bounds__(256) void qkv_gemm(QkvArgs a) {
  __shared__ unsigned char lds[32768];  // A tile 16KB | W tile 16KB
  const int z = blockIdx.z;
  const unsigned short* __restrict__ A = a.A[z];
  const unsigned short* __restrict__ B = a.W[z];
  const float* __restrict__ bias = a.bias[z];
  unsigned short* __restrict__ dst = a.dst[z];
  const float scale = a.scale[z];

  const int tid = threadIdx.x;
  const int lane = tid & 63;
  const int w = tid >> 6;
  const int wr = w >> 1, wc = w & 1;
  const int c = lane & 15, g = lane >> 4;
  const int m0 = blockIdx.x * 128;
  const int n0 = blockIdx.y * 128;

  f32x4 acc[4][4] = {};

  for (int kt = 0; kt < DMODEL / 64; ++kt) {
#pragma unroll
    for (int p = 0; p < 4; ++p) {
      const int te = p * 256 + tid;
      const int row = te >> 3;
      const int sb = ((te & 7) * 16) ^ ((row & 7) << 4);
      gload_lds16(A + (size_t)(m0 + row) * DMODEL + kt * 64 + (sb >> 1), &lds[te * 16]);
      gload_lds16(B + (size_t)(n0 + row) * DMODEL + kt * 64 + (sb >> 1), &lds[16384 + te * 16]);
    }
    __syncthreads();

    bf16x8 af[4][2], bfr[4][2];
#pragma unroll
    for (int mb = 0; mb < 4; ++mb)
#pragma unroll
      for (int ks = 0; ks < 2; ++ks) {
        const int row = wr * 64 + mb * 16 + c;
        const int byte = (ks * 64 + g * 16) ^ ((row & 7) << 4);
        af[mb][ks] = *reinterpret_cast<const bf16x8*>(&lds[row * 128 + byte]);
      }
#pragma unroll
    for (int nb = 0; nb < 4; ++nb)
#pragma unroll
      for (int ks = 0; ks < 2; ++ks) {
        const int row = wc * 64 + nb * 16 + c;
        const int byte = (ks * 64 + g * 16) ^ ((row & 7) << 4);
        bfr[nb][ks] = *reinterpret_cast<const bf16x8*>(&lds[16384 + row * 128 + byte]);
      }
    __builtin_amdgcn_s_setprio(1);
#pragma unroll
    for (int ks = 0; ks < 2; ++ks)
#pragma unroll
      for (int mb = 0; mb < 4; ++mb)
#pragma unroll
        for (int nb = 0; nb < 4; ++nb)
          acc[mb][nb] = __builtin_amdgcn_mfma_f32_16x16x32_bf16(
              af[mb][ks], bfr[nb][ks], acc[mb][nb], 0, 0, 0);
    __builtin_amdgcn_s_setprio(0);
    __syncthreads();
  }

#pragma unroll
  for (int mb = 0; mb < 4; ++mb) {
#pragma unroll
    for (int nb = 0; nb < 4; ++nb) {
      const int n = n0 + wc * 64 + nb * 16 + c;
      const float bv = bias[n];
#pragma unroll
      for (int r = 0; r < 4; ++r) {
        const int m = m0 + wr * 64 + mb * 16 + g * 4 + r;
        const float v = (acc[mb][nb][r] + bv) * scale;
        const int hh = n >> 6, hd = n & 63;
        if (z != 2) {
          dst[((size_t)hh * S_LEN + m) * HD + hd] = f2bf(v);
        } else {
          const int mp = (m & ~12) | ((m & 4) << 1) | ((m & 8) >> 1);
          dst[((size_t)hh * HD + hd) * S_LEN + mp] = f2bf(v);
        }
      }
    }
  }
}

// ---------------- output projection: fp32 out ----------------
__global__ __launch_bounds__(256) void gemm_out(
    const unsigned short* __restrict__ A, const unsigned short* __restrict__ B,
    const float* __restrict__ bias, float* __restrict__ dst) {
  __shared__ unsigned char lds[32768];
  const int tid = threadIdx.x;
  const int lane = tid & 63;
  const int w = tid >> 6;
  const int wr = w >> 1, wc = w & 1;
  const int c = lane & 15, g = lane >> 4;
  const int m0 = blockIdx.x * 128;
  const int n0 = blockIdx.y * 128;

  f32x4 acc[4][4] = {};

  for (int kt = 0; kt < DMODEL / 64; ++kt) {
#pragma unroll
    for (int p = 0; p < 4; ++p) {
      const int te = p * 256 + tid;
      const int row = te >> 3;
      const int sb = ((te & 7) * 16) ^ ((row & 7) << 4);
      gload_lds16(A + (size_t)(m0 + row) * DMODEL + kt * 64 + (sb >> 1), &lds[te * 16]);
      gload_lds16(B + (size_t)(n0 + row) * DMODEL + kt * 64 + (sb >> 1), &lds[16384 + te * 16]);
    }
    __syncthreads();

    bf16x8 af[4][2], bfr[4][2];
#pragma unroll
    for (int mb = 0; mb < 4; ++mb)
#pragma unroll
      for (int ks = 0; ks < 2; ++ks) {
        const int row = wr * 64 + mb * 16 + c;
        const int byte = (ks * 64 + g * 16) ^ ((row & 7) << 4);
        af[mb][ks] = *reinterpret_cast<const bf16x8*>(&lds[row * 128 + byte]);
      }
#pragma unroll
    for (int nb = 0; nb < 4; ++nb)
#pragma unroll
      for (int ks = 0; ks < 2; ++ks) {
        const int row = wc * 64 + nb * 16 + c;
        const int byte = (ks * 64 + g * 16) ^ ((row & 7) << 4);
        bfr[nb][ks] = *reinterpret_cast<const bf16x8*>(&lds[16384 + row * 128 + byte]);
      }
    __builtin_amdgcn_s_setprio(1);
#pragma unroll
    for (int ks = 0; ks < 2; ++ks)
#pragma unroll
      for (int mb = 0; mb < 4; ++mb)
#pragma unroll
        for (int nb = 0; nb < 4; ++nb)
          acc[mb][nb] = __builtin_amdgcn_mfma_f32_16x16x32_bf16(
              af[mb][ks], bfr[nb][ks], acc[mb][nb], 0, 0, 0);
    __builtin_amdgcn_s_setprio(0);
    __syncthreads();
  }

#pragma unroll
  for (int mb = 0; mb < 4; ++mb)
#pragma unroll
    for (int nb = 0; nb < 4; ++nb) {
      const int n = n0 + wc * 64 + nb * 16 + c;
      const float bv = bias[n];
#pragma unroll
      for (int r = 0; r < 4; ++r) {
        const int m = m0 + wr * 64 + mb * 16 + g * 4 + r;
        dst[(size_t)m * DMODEL + n] = acc[mb][nb][r] + bv;
      }
    }
}

// ---------------- flash attention, 8-wave blocks, kv-split-4 ------------
// grid = (S/256, H, 4); block = 512 (8 waves x 32 q). KV tile 64.
// K/V staging amortized over 256 q-rows (2 loads/thread/tile).
// launch_bounds min-waves = 4 (VGPR cap 128): r8's (512,6) capped VGPR at
// 85 < the ~100 this kernel needs -> accumulator spill to scratch (1.46
// GB/dispatch, 339us). NEVER floor occupancy above the register budget.
// Transposed-chunk LDS (conflict-free b128). Triple buffer, one barrier
// per kt, prefetch depth 2, counted vmcnt(2) (r6-verified schedule).
__global__ __launch_bounds__(512, 4) void attn_kernel(
    const unsigned short* __restrict__ qh,   // [H][S][64], pre-scaled
    const unsigned short* __restrict__ kh,   // [H][S][64]
    const unsigned short* __restrict__ vtp,  // [H][64][S], kv bits2<->3 swapped
    _Float16* __restrict__ pacc,             // [4][H][S][64] (values /64)
    float* __restrict__ prs) {               // [4][H][S]     (values /64)
  __shared__ unsigned char lds[49152];  // 3 x (K 8KB | Vt 8KB)
  const int tid = threadIdx.x;
  const int lane = tid & 63;
  const int w = tid >> 6;          // 0..7
  const int c5 = lane & 31;
  const int h2 = lane >> 5;
  const int hh = blockIdx.y;
  const int split = blockIdx.z;
  const int qw = blockIdx.x * 256 + w * 32;
  const int kv0 = split * (S_LEN / 4);
  const int nkt = (S_LEN / 4) / 64;   // 16

  // Q B-fragments: col = q = c5, k = ks*16 + h2*8 + i
  bf16x8 qa[4];
#pragma unroll
  for (int ks = 0; ks < 4; ++ks)
    qa[ks] = *reinterpret_cast<const bf16x8*>(
        qh + ((size_t)hh * S_LEN + qw + c5) * HD + ks * 16 + h2 * 8);

  // transposed-chunk staging: LDS[tid*16] <- K[row = tid&63][kchunk = tid>>6]
  // 512 threads cover the full 64x64 tile (8 kchunks) in ONE load each.
  const unsigned short* ksrc =
      kh + ((size_t)hh * S_LEN + kv0 + (tid & 63)) * HD + (tid >> 6) * 8;
  const unsigned short* vsrc =
      vtp + ((size_t)hh * HD + (tid & 63)) * S_LEN + kv0 + (tid >> 6) * 8;
  const int dL = tid * 16;

  auto stage = [&](int bo) {
    gload_lds16(ksrc, &lds[bo + dL]);
    gload_lds16(vsrc, &lds[bo + 8192 + dL]);
    ksrc += 64 * HD;
    vsrc += 64;
  };

  // prologue: stage tiles 0,1 into bufs 0,1 (4 loads in flight)
  stage(0);
  stage(16384);

  f32x16 accO[2] = {};
  float rs0 = 0.f, rs1 = 0.f, rs2 = 0.f, rs3 = 0.f;

  auto compute = [&](const unsigned char* Kb, const unsigned char* Vb) {
    // S^T[kv][q] = mfma(K as A, Q as B)
    f32x16 s0 = {}, s1 = {};
    __builtin_amdgcn_s_setprio(1);
#pragma unroll
    for (int ks = 0; ks < 4; ++ks) {
      const unsigned char* kbase = Kb + (ks * 2 + h2) * 1024 + c5 * 16;
      const bf16x8 k0 = *reinterpret_cast<const bf16x8*>(kbase);
      const bf16x8 k1 = *reinterpret_cast<const bf16x8*>(kbase + 512);
      s0 = MFMA32(k0, qa[ks], s0);
      s1 = MFMA32(k1, qa[ks], s1);
    }
    __builtin_amdgcn_s_setprio(0);

    // fused softmax + PV per 8-kv quadrant
#pragma unroll
    for (int t = 0; t < 2; ++t)
#pragma unroll
      for (int ss = 0; ss < 2; ++ss) {
        const unsigned char* vbase = Vb + (t * 4 + ss * 2 + h2) * 1024 + c5 * 16;
        const bf16x8 va0 = *reinterpret_cast<const bf16x8*>(vbase);
        const bf16x8 va1 = *reinterpret_cast<const bf16x8*>(vbase + 512);
        bf16x8 pb;
        float racc = 0.f;
#pragma unroll
        for (int r = 0; r < 8; ++r) {
          const float e = EXP2F(t ? s1[ss * 8 + r] : s0[ss * 8 + r]);
          racc += e;
          pb[r] = (__bf16)e;
        }
        if (t == 0) { if (ss == 0) rs0 += racc; else rs1 += racc; }
        else        { if (ss == 0) rs2 += racc; else rs3 += racc; }
        __builtin_amdgcn_s_setprio(1);
        accO[0] = MFMA32(va0, pb, accO[0]);
        accO[1] = MFMA32(va1, pb, accO[1]);
        __builtin_amdgcn_s_setprio(0);
      }
  };

  int boC = 0;          // buffer being computed (tile t)
  int boS = 32768;      // buffer to stage into (tile t+2)
  for (int t = 0; t < nkt; ++t) {
    if (t + 2 < nkt) {
      asm volatile("s_waitcnt vmcnt(2)" ::: "memory");
      __builtin_amdgcn_sched_barrier(0);
      __builtin_amdgcn_s_barrier();
      __builtin_amdgcn_sched_barrier(0);
      stage(boS);
    } else if (t + 1 < nkt) {
      asm volatile("s_waitcnt vmcnt(2)" ::: "memory");
      __builtin_amdgcn_sched_barrier(0);
      __builtin_amdgcn_s_barrier();
      __builtin_amdgcn_sched_barrier(0);
    } else {
      asm volatile("s_waitcnt vmcnt(0)" ::: "memory");
      __builtin_amdgcn_sched_barrier(0);
      __builtin_amdgcn_s_barrier();
      __builtin_amdgcn_sched_barrier(0);
    }
    compute(&lds[boC], &lds[boC + 8192]);
    boC += 16384; if (boC == 49152) boC = 0;
    boS += 16384; if (boS == 49152) boS = 0;
  }

  // partial sums out (scaled by 1/64 for f16 range)
  float rsA = (rs0 + rs1) + (rs2 + rs3);
  rsA += __shfl_xor(rsA, 32);
  const size_t hqbase = ((size_t)split * NHEAD + hh) * S_LEN + qw + c5;
  if (h2 == 0) prs[hqbase] = rsA * 0.015625f;
#pragma unroll
  for (int dt = 0; dt < 2; ++dt)
#pragma unroll
    for (int rr = 0; rr < 4; ++rr) {
      f16x4 o;
#pragma unroll
      for (int j = 0; j < 4; ++j)
        o[j] = (_Float16)(accO[dt][rr * 4 + j] * 0.015625f);
      *reinterpret_cast<f16x4*>(
          pacc + hqbase * 64 + dt * 32 + rr * 8 + h2 * 4) = o;
    }
}

// ---------------- combine 4 kv-split partials -> attb bf16 ---------------
__global__ __launch_bounds__(256) void combine_kernel(
    const _Float16* __restrict__ pacc, const float* __restrict__ prs,
    unsigned short* __restrict__ attb) {
  const int idx = blockIdx.x * 256 + threadIdx.x;  // 786432 total
  const int hq = idx >> 4;            // h*4096 + q
  const int d4 = (idx & 15) * 4;
  const int h = hq >> 12;
  const int q = hq & 4095;
  const int HS = NHEAD * S_LEN;
  const size_t o0 = (size_t)hq * 64 + d4;
  float acc4[4] = {0.f, 0.f, 0.f, 0.f};
  float rs = 0.f;
#pragma unroll
  for (int k = 0; k < 4; ++k) {
    const f16x4 av = *reinterpret_cast<const f16x4*>(pacc + o0 + (size_t)k * HS * 64);
#pragma unroll
    for (int j = 0; j < 4; ++j) acc4[j] += (float)av[j];
    rs += prs[hq + k * HS];
  }
  const float inv = 1.f / rs;
  u16x4 ov;
#pragma unroll
  for (int j = 0; j < 4; ++j) ov[j] = f2bf(acc4[j] * inv);
  *reinterpret_cast<u16x4*>(attb + (size_t)q * DMODEL + h * HD + d4) = ov;
}

// ---------------- launch ----------------
extern "C" void kernel_launch(void* const* d_in, const int* in_sizes, int n_in,
                              void* d_out, int out_size, void* d_ws, size_t ws_size,
                              hipStream_t stream) {
  (void)in_sizes; (void)n_in; (void)out_size;
  const float* q  = (const float*)d_in[0];
  const float* k  = (const float*)d_in[1];
  const float* v  = (const float*)d_in[2];
  const float* Wq = (const float*)d_in[3];
  const float* bq = (const float*)d_in[4];
  const float* Wk = (const float*)d_in[5];
  const float* bk = (const float*)d_in[6];
  const float* Wv = (const float*)d_in[7];
  const float* bv = (const float*)d_in[8];
  const float* Wo = (const float*)d_in[9];
  const float* bo = (const float*)d_in[10];
  float* out = (float*)d_out;

  const size_t SD = (size_t)S_LEN * DMODEL;    // 3145728
  const size_t DD = (size_t)DMODEL * DMODEL;   // 589824
  if (ws_size < (7 * SD + 4 * DD) * 2) return;

  // ws layout (u16 units). Liveness ledger:
  //  pacc [0..4SD)  f16 [4][H][S][64] -- written by attn, read by combine.
  //    Aliases (all dead before attn runs): qbf [0..SD), kbf [SD..2SD),
  //    vbf [2SD..3SD) (dead after qkv); wqb/wkb/wvb [3SD..3SD+3DD)
  //    (dead after qkv; 3SD+3DD < 4SD).
  //  qhb [4SD..5SD)  -- read by attn, dead after; attb aliases it
  //    (written by combine, read by gemm_out).
  //  khb [5SD..6SD), vtb [6SD..7SD) -- dead after attn.
  //  prs [7SD..7SD+393216)  f32 [4][H][S].
  //  wob [7SD+393216..+DD)  -- live until gemm_out. Fits: 393216+DD < 4DD.
  unsigned short* ws   = (unsigned short*)d_ws;
  unsigned short* qbf  = ws;
  unsigned short* kbf  = ws + SD;
  unsigned short* vbf  = ws + 2 * SD;
  unsigned short* wqb  = ws + 3 * SD;
  unsigned short* wkb  = ws + 3 * SD + DD;
  unsigned short* wvb  = ws + 3 * SD + 2 * DD;
  unsigned short* qhb  = ws + 4 * SD;   // [H][S][64]
  unsigned short* khb  = ws + 5 * SD;   // [H][S][64]
  unsigned short* vtb  = ws + 6 * SD;   // [H][64][S] (kv-permuted)
  float*          prs  = (float*)(ws + 7 * SD);          // [4][H][S]
  unsigned short* wob  = ws + 7 * SD + 393216;
  _Float16*       pacc = (_Float16*)ws;                  // [4][H][S][64]
  unsigned short* attb = ws + 4 * SD;                    // alias qhb

  CvtArgs ca;
  ca.src[0] = q;  ca.dst[0] = qbf; ca.n[0] = (int)SD;
  ca.src[1] = k;  ca.dst[1] = kbf; ca.n[1] = (int)SD;
  ca.src[2] = v;  ca.dst[2] = vbf; ca.n[2] = (int)SD;
  ca.src[3] = Wq; ca.dst[3] = wqb; ca.n[3] = (int)DD;
  ca.src[4] = Wk; ca.dst[4] = wkb; ca.n[4] = (int)DD;
  ca.src[5] = Wv; ca.dst[5] = wvb; ca.n[5] = (int)DD;
  ca.src[6] = Wo; ca.dst[6] = wob; ca.n[6] = (int)DD;
  cvt_kernel<<<dim3(1536, 7), 256, 0, stream>>>(ca);

  QkvArgs qa;
  qa.A[0] = qbf; qa.W[0] = wqb; qa.bias[0] = bq; qa.dst[0] = qhb;
  qa.scale[0] = 0.18033688011112042f;  // (1/8) * log2(e)
  qa.A[1] = kbf; qa.W[1] = wkb; qa.bias[1] = bk; qa.dst[1] = khb;
  qa.scale[1] = 1.0f;
  qa.A[2] = vbf; qa.W[2] = wvb; qa.bias[2] = bv; qa.dst[2] = vtb;
  qa.scale[2] = 1.0f;
  qkv_gemm<<<dim3(32, 6, 3), 256, 0, stream>>>(qa);

  attn_kernel<<<dim3(S_LEN / 256, NHEAD, 4), 512, 0, stream>>>(
      qhb, khb, vtb, pacc, prs);

  combine_kernel<<<dim3((NHEAD * S_LEN * 16) / 256), 256, 0, stream>>>(
      pacc, prs, attb);

  gemm_out<<<dim3(32, 6), 256, 0, stream>>>(attb, wob, bo, out);
}